// Round 17
// baseline (293.759 us; speedup 1.0000x reference)
//
#include <hip/hip_runtime.h>
#include <hip/hip_bf16.h>
#include <math.h>

typedef __bf16 bf16;
typedef __attribute__((ext_vector_type(8))) __bf16 bf16x8;
typedef __attribute__((ext_vector_type(4))) float f32x4;
typedef __attribute__((ext_vector_type(16))) float f32x16;

#define DEV __device__ __forceinline__

// ---------------------------------------------------------------------------
// async global->LDS, 16B per lane. LDS dest is wave-uniform base + lane*16.
DEV void gload16(const void* g, void* l) {
    __builtin_amdgcn_global_load_lds(
        (__attribute__((address_space(1))) void*)(void*)g,
        (__attribute__((address_space(3))) void*)l, 16, 0, 0);
}

DEV unsigned pk2(float a, float b) {
    union { bf16 h[2]; unsigned u; } z;
    z.h[0] = (bf16)a; z.h[1] = (bf16)b;
    return z.u;
}

// swap a's hi-32-lane contents with b's lo-32-lane contents.
DEV void plswap(unsigned& a, unsigned& b) {
    asm volatile("v_permlane32_swap_b32 %0, %1" : "+v"(a), "+v"(b));
}

DEV f32x16 mfma32(bf16x8 a, bf16x8 b, f32x16 c) {
    return __builtin_amdgcn_mfma_f32_32x32x16_bf16(a, b, c, 0, 0, 0);
}

// ---------------------------------------------------------------------------
// fp32 -> bf16 conversion for x + all 4 weights, one launch, 5 segments.
__global__ __launch_bounds__(256) void cvtall_kernel(const float* __restrict__ x,
                                                     const float* __restrict__ w0,
                                                     const float* __restrict__ w1,
                                                     const float* __restrict__ w2,
                                                     const float* __restrict__ w3,
                                                     bf16* __restrict__ xb,
                                                     bf16* __restrict__ wb) {
    const int seg = blockIdx.y;
    const float* in;
    bf16* o;
    int n8;
    if (seg == 0) { in = x; o = xb; n8 = 1048576; }
    else {
        in = (seg == 1) ? w0 : (seg == 2) ? w1 : (seg == 3) ? w2 : w3;
        o = wb + (size_t)(seg - 1) * 4194304;
        n8 = 524288;
    }
    for (int i = blockIdx.x * 256 + threadIdx.x; i < n8; i += 512 * 256) {
        const float4* p = (const float4*)(in + (size_t)i * 8);
        float4 a = p[0], b = p[1];
        bf16x8 v;
        v[0] = (bf16)a.x; v[1] = (bf16)a.y; v[2] = (bf16)a.z; v[3] = (bf16)a.w;
        v[4] = (bf16)b.x; v[5] = (bf16)b.y; v[6] = (bf16)b.z; v[7] = (bf16)b.w;
        *(bf16x8*)(o + (size_t)i * 8) = v;
    }
}

// ---------------------------------------------------------------------------
// Fused QKV GEMM: 256x384 tile, BK=32, 8 waves (2M x 4N), 32x32x16 MFMA,
// barrier-thinned. r17: 2-DEEP buffer (80KB exactly) -> 2 blocks/CU
// (3-ring's 120KB forced 1 block/CU; cross-block drift is the stall-hider).
// Loads for t+1 issue at iter top and have the full ~3000-cyc tile to land;
// the gate is vmcnt(0)+barrier (attn's proven 2-buffer pattern).
__global__ __launch_bounds__(512, 2) void gemm_qkv(const bf16* __restrict__ A,
                                                   const bf16* __restrict__ Bg,
                                                   bf16* __restrict__ outq) {
    __shared__ __align__(16) bf16 As[2][256 * 32];
    __shared__ __align__(16) bf16 Bs[2][384 * 32];
    const int tid = threadIdx.x, lane = tid & 63, wv = tid >> 6;
    const int q31 = lane & 31, h5 = lane >> 5;
    const int wm = wv >> 2, wn = wv & 3;
    const int K = 2048;

    int lin = blockIdx.x;
    int swz = (lin & 7) * 32 + (lin >> 3);
    const int tm = (swz >> 4) * 256;
    const int tn = (swz & 15) * 384;

    f32x16 acc[4][3] = {};

    auto stageA = [&](int t, int buf) {
#pragma unroll
        for (int l = 0; l < 2; ++l) {
            int chunk = l * 8 + wv;
            int row = chunk * 16 + (lane >> 2);
            int cb = ((lane & 3) * 16) ^ (((row >> 1) & 3) << 4);
            gload16((const char*)(A + (size_t)(tm + row) * K + t * 32) + cb,
                    (char*)(As[buf]) + chunk * 1024);
        }
    };
    auto stageB = [&](int t, int buf) {
#pragma unroll
        for (int l = 0; l < 3; ++l) {
            int chunk = l * 8 + wv;
            int row = chunk * 16 + (lane >> 2);
            int cb = ((lane & 3) * 16) ^ (((row >> 1) & 3) << 4);
            gload16((const char*)(Bg + (size_t)(tn + row) * K + t * 32) + cb,
                    (char*)(Bs[buf]) + chunk * 1024);
        }
    };
    auto rdA = [&](int buf, int mb, int ks) -> bf16x8 {
        int row = wm * 128 + mb * 32 + q31;
        int off = (ks * 32 + h5 * 16) ^ (((row >> 1) & 3) << 4);
        return *(const bf16x8*)((const char*)(As[buf]) + row * 64 + off);
    };
    auto rdB = [&](int buf, int nb, int ks) -> bf16x8 {
        int row = wn * 96 + nb * 32 + q31;
        int off = (ks * 32 + h5 * 16) ^ (((row >> 1) & 3) << 4);
        return *(const bf16x8*)((const char*)(Bs[buf]) + row * 64 + off);
    };

    // prologue: tile 0 staged and drained
    stageA(0, 0); stageB(0, 0);
    asm volatile("s_waitcnt vmcnt(0)" ::: "memory");
    __builtin_amdgcn_s_barrier();

    for (int t = 0; t < 64; ++t) {
        const int cur = t & 1;
        // issue next tile's loads first — they fly across this tile's compute
        if (t < 63) { stageA(t + 1, cur ^ 1); stageB(t + 1, cur ^ 1); }

        bf16x8 af[2][2], bfr[3][2];
#pragma unroll
        for (int mb = 0; mb < 2; ++mb)
#pragma unroll
            for (int ks = 0; ks < 2; ++ks) af[mb][ks] = rdA(cur, mb, ks);
#pragma unroll
        for (int nb = 0; nb < 3; ++nb)
#pragma unroll
            for (int ks = 0; ks < 2; ++ks) bfr[nb][ks] = rdB(cur, nb, ks);
        asm volatile("s_waitcnt lgkmcnt(0)" ::: "memory");
        __builtin_amdgcn_sched_barrier(0);
        __builtin_amdgcn_s_setprio(1);
#pragma unroll
        for (int mb = 0; mb < 2; ++mb)
#pragma unroll
            for (int nb = 0; nb < 3; ++nb)
#pragma unroll
                for (int ks = 0; ks < 2; ++ks)
                    acc[mb][nb] = mfma32(af[mb][ks], bfr[nb][ks], acc[mb][nb]);
        __builtin_amdgcn_s_setprio(0);
#pragma unroll
        for (int mb = 0; mb < 2; ++mb)
#pragma unroll
            for (int ks = 0; ks < 2; ++ks) af[mb][ks] = rdA(cur, 2 + mb, ks);
        asm volatile("s_waitcnt lgkmcnt(0)" ::: "memory");
        __builtin_amdgcn_sched_barrier(0);
        __builtin_amdgcn_s_setprio(1);
#pragma unroll
        for (int mb = 0; mb < 2; ++mb)
#pragma unroll
            for (int nb = 0; nb < 3; ++nb)
#pragma unroll
                for (int ks = 0; ks < 2; ++ks)
                    acc[2 + mb][nb] = mfma32(af[mb][ks], bfr[nb][ks], acc[2 + mb][nb]);
        __builtin_amdgcn_s_setprio(0);
        // gate: drain t+1's loads (they had the whole tile to land) + barrier
        asm volatile("s_waitcnt vmcnt(0)" ::: "memory");
        __builtin_amdgcn_s_barrier();
    }

#pragma unroll
    for (int mb = 0; mb < 4; ++mb)
#pragma unroll
        for (int nb = 0; nb < 3; ++nb) {
            int colbase = tn + wn * 96 + nb * 32;
            bf16* op = outq + (size_t)(colbase >> 11) * 8388608 +
                       (colbase & 2047) + q31;
#pragma unroll
            for (int r = 0; r < 16; ++r) {
                int row = tm + wm * 128 + mb * 32 + (r & 3) + 8 * (r >> 2) + 4 * h5;
                op[(size_t)row * 2048] = (bf16)acc[mb][nb][r];
            }
        }
}

// ---------------------------------------------------------------------------
// C[M,N] = A[M,K] @ B[N,K]^T. 128x128 tile, BK=64, 4 waves. Wo GEMM.
template <bool F32OUT>
__global__ __launch_bounds__(256) void gemm_bt(const bf16* __restrict__ A,
                                               const bf16* __restrict__ B,
                                               void* __restrict__ Cout,
                                               int M, int N, int K) {
    __shared__ __align__(16) bf16 As[128 * 64];
    __shared__ __align__(16) bf16 Bs[128 * 64];
    const int tid = threadIdx.x, lane = tid & 63, wv = tid >> 6;
    int lin = blockIdx.y * 16 + blockIdx.x;
    int swz = (lin & 7) * 64 + (lin >> 3);
    const int tm = (swz >> 4) * 128, tn = (swz & 15) * 128;
    const int wr = (wv >> 1) * 64, wc = (wv & 1) * 64;

    f32x4 acc[4][4] = {};
    const int scb = (lane & 7) * 16;

    for (int k0 = 0; k0 < K; k0 += 64) {
#pragma unroll
        for (int i = 0; i < 4; ++i) {
            int chunk = wv * 4 + i;
            int row = chunk * 8 + (lane >> 3);
            int cb = scb ^ ((row & 7) << 4);
            gload16((const char*)(A + (size_t)(tm + row) * K + k0) + cb,
                    (char*)As + chunk * 1024);
            gload16((const char*)(B + (size_t)(tn + row) * K + k0) + cb,
                    (char*)Bs + chunk * 1024);
        }
        __syncthreads();
#pragma unroll
        for (int kk = 0; kk < 2; ++kk) {
            bf16x8 af[4], bfr[4];
#pragma unroll
            for (int m = 0; m < 4; ++m) {
                int row = wr + m * 16 + (lane & 15);
                int cb = (kk * 64 + ((lane >> 4) * 16)) ^ ((row & 7) << 4);
                af[m] = *(const bf16x8*)((const char*)As + row * 128 + cb);
            }
#pragma unroll
            for (int n = 0; n < 4; ++n) {
                int row = wc + n * 16 + (lane & 15);
                int cb = (kk * 64 + ((lane >> 4) * 16)) ^ ((row & 7) << 4);
                bfr[n] = *(const bf16x8*)((const char*)Bs + row * 128 + cb);
            }
#pragma unroll
            for (int m = 0; m < 4; ++m)
#pragma unroll
                for (int n = 0; n < 4; ++n)
                    acc[m][n] = __builtin_amdgcn_mfma_f32_16x16x32_bf16(
                        af[m], bfr[n], acc[m][n], 0, 0, 0);
        }
        __syncthreads();
    }
#pragma unroll
    for (int m = 0; m < 4; ++m)
#pragma unroll
        for (int n = 0; n < 4; ++n)
#pragma unroll
            for (int r = 0; r < 4; ++r) {
                int row = tm + wr + m * 16 + (lane >> 4) * 4 + r;
                int col = tn + wc + n * 16 + (lane & 15);
                if (F32OUT)
                    ((float*)Cout)[(size_t)row * N + col] = acc[m][n][r];
                else
                    ((bf16*)Cout)[(size_t)row * N + col] = (bf16)acc[m][n][r];
            }
}

// ---------------------------------------------------------------------------
// RoPE + RMSNorm(*1.2), in-place. q pre-scaled by (1/sqrt(128))*log2(e).
__global__ __launch_bounds__(256) void rope_rms(bf16* __restrict__ q,
                                                bf16* __restrict__ k,
                                                const float* __restrict__ cosp,
                                                const float* __restrict__ sinp) {
    int gw = blockIdx.x * 4 + (threadIdx.x >> 6);
    int lane = threadIdx.x & 63;
    bf16* base = (blockIdx.y == 0) ? q : k;
    int m = gw >> 4, h = gw & 15;
    int s = m & 2047;
    bf16* p = base + (size_t)m * 2048 + h * 128;
    float x1 = (float)p[lane], x2 = (float)p[lane + 64];
    float c = cosp[s * 64 + lane], si = sinp[s * 64 + lane];
    float r1 = x1 * c + x2 * si;
    float r2 = x2 * c - x1 * si;
    float ss = r1 * r1 + r2 * r2;
#pragma unroll
    for (int msk = 1; msk < 64; msk <<= 1) ss += __shfl_xor(ss, msk);
    float sc = rsqrtf(ss * (1.0f / 128.0f) + 1.1920928955078125e-07f) * 1.2f;
    if (blockIdx.y == 0) sc *= (0.08838834764831845f * 1.4426950408889634f);
    p[lane] = (bf16)(r1 * sc);
    p[lane + 64] = (bf16)(r2 * sc);
}

// ---------------------------------------------------------------------------
// Flash attention fwd (r15 exact, the 283.8 best): 32x32x16 MFMA, swapped
// QK^T, P in registers via permlane32_swap. 8 waves x 32 q = 256 q/block.
__global__ __launch_bounds__(512, 2) void attn_kernel(const bf16* __restrict__ q,
                                                      const bf16* __restrict__ k,
                                                      const bf16* __restrict__ v,
                                                      bf16* __restrict__ y) {
    __shared__ __align__(16) bf16 Ks[2][64 * 128];
    __shared__ __align__(16) bf16 Vt[2][128][72];

    const int tid = threadIdx.x, lane = tid & 63, wv = tid >> 6;
    const int q31 = lane & 31, h5 = lane >> 5;

    int wgid = blockIdx.y * 8 + blockIdx.x;
    int xcd = wgid & 7, j = wgid >> 3;
    const int bh = xcd * 4 + (j >> 3);
    const int qblk = j & 7;
    const int b = bh >> 4, h = bh & 15;
    const int q0 = qblk * 256;

    const bf16* qptr = q + (size_t)(b * 2048 + q0 + wv * 32 + q31) * 2048 +
                       h * 128 + h5 * 8;
    bf16x8 qf[8];
#pragma unroll
    for (int ks = 0; ks < 8; ++ks) qf[ks] = *(const bf16x8*)(qptr + ks * 16);

    float mrun = -INFINITY, lrun = 0.f;
    f32x16 acco[4] = {};

    const int p = tid & 63, rg = tid >> 6;
    const bf16* vbase = v + (size_t)(b * 2048 + rg * 8) * 2048 + h * 128 + 2 * p;
    const bf16* kbase = k + (size_t)(b * 2048) * 2048 + h * 128;
    const int vx = (((p >> 2) & 1) << 4) ^ (((p >> 3) & 1) << 5);

    unsigned u[8];

    auto stageK = [&](int t, int buf) {
#pragma unroll
        for (int i = 0; i < 2; ++i) {
            int chunk = wv * 2 + i;
            int row = chunk * 4 + (lane >> 4);
            int cb = ((lane & 15) * 16) ^ ((row & 7) << 4);
            gload16((const char*)(kbase + (size_t)(t * 64 + row) * 2048) + cb,
                    (char*)(Ks[buf]) + chunk * 1024);
        }
    };
    auto loadV = [&](int t) {
        const bf16* vp = vbase + (size_t)(t * 64) * 2048;
#pragma unroll
        for (int jj = 0; jj < 8; ++jj)
            u[jj] = *(const unsigned*)(vp + (size_t)jj * 2048);
    };
    auto writeV = [&](int buf) {
        union { unsigned short s[8]; bf16x8 v8; } lo, hi;
#pragma unroll
        for (int jj = 0; jj < 8; ++jj) {
            lo.s[jj] = (unsigned short)(u[jj] & 0xffff);
            hi.s[jj] = (unsigned short)(u[jj] >> 16);
        }
        char* r0 = (char*)(&Vt[buf][2 * p][0]);
        char* r1 = (char*)(&Vt[buf][2 * p + 1][0]);
        *(bf16x8*)(r0 + ((rg * 16) ^ vx)) = lo.v8;
        *(bf16x8*)(r1 + ((rg * 16) ^ vx)) = hi.v8;
    };

    stageK(0, 0);
    loadV(0);
    writeV(0);
    __syncthreads();

    const int rx = (((q31 >> 3) & 1) << 4) ^ (((q31 >> 4) & 1) << 5);

    for (int t = 0; t < 32; ++t) {
        const int c = t & 1;
        if (t < 31) {
            stageK(t + 1, c ^ 1);
            loadV(t + 1);
        }

        f32x16 st[2];
        __builtin_amdgcn_s_setprio(1);
#pragma unroll
        for (int kvb = 0; kvb < 2; ++kvb) {
            f32x16 a = {};
#pragma unroll
            for (int ks = 0; ks < 8; ++ks) {
                int row = kvb * 32 + q31;
                int cb = (32 * ks + 16 * h5) ^ ((row & 7) << 4);
                const bf16x8 kf =
                    *(const bf16x8*)((const char*)(Ks[c]) + row * 256 + cb);
                a = __builtin_amdgcn_mfma_f32_32x32x16_bf16(kf, qf[ks], a, 0, 0, 0);
            }
            st[kvb] = a;
        }
        __builtin_amdgcn_s_setprio(0);

        float t8[8];
#pragma unroll
        for (int r = 0; r < 8; ++r)
            t8[r] = fmaxf(fmaxf(st[0][r], st[0][r + 8]),
                          fmaxf(st[1][r], st[1][r + 8]));
        float mx = fmaxf(fmaxf(fmaxf(t8[0], t8[1]), fmaxf(t8[2], t8[3])),
                         fmaxf(fmaxf(t8[4], t8[5]), fmaxf(t8[6], t8[7])));
        mx = fmaxf(mx, __shfl_xor(mx, 32));

        if (__any(mx - mrun > 8.0f)) {
            float mn = fmaxf(mrun, mx);
            float alpha = exp2f(mrun - mn);
            mrun = mn;
            lrun *= alpha;
#pragma unroll
            for (int r = 0; r < 16; ++r) {
                int qr = (r & 3) + 8 * (r >> 2) + 4 * h5;
                float al = __shfl(alpha, qr);
                acco[0][r] *= al; acco[1][r] *= al;
                acco[2][r] *= al; acco[3][r] *= al;
            }
        }

        unsigned w[2][8];
        float rsa = 0.f, rsb = 0.f;
#pragma unroll
        for (int kvb = 0; kvb < 2; ++kvb)
#pragma unroll
            for (int i = 0; i < 8; ++i) {
                float p0 = exp2f(st[kvb][2 * i] - mrun);
                float p1 = exp2f(st[kvb][2 * i + 1] - mrun);
                if (i & 1) rsb += p0 + p1; else rsa += p0 + p1;
                w[kvb][i] = pk2(p0, p1);
            }
        float rs = rsa + rsb;
        rs += __shfl_xor(rs, 32);
        lrun += rs;

        __builtin_amdgcn_s_setprio(1);
#pragma unroll
        for (int b2 = 0; b2 < 2; ++b2)
#pragma unroll
            for (int ksl = 0; ksl < 2; ++ksl) {
                const int ks = b2 * 2 + ksl, u0 = ksl * 4;
                unsigned f0 = w[b2][u0 + 0], f2 = w[b2][u0 + 2];
                unsigned f1 = w[b2][u0 + 1], f3 = w[b2][u0 + 3];
                plswap(f0, f2);
                plswap(f1, f3);
                union { unsigned uu[4]; bf16x8 v8; } fr;
                fr.uu[0] = f0; fr.uu[1] = f1; fr.uu[2] = f2; fr.uu[3] = f3;
#pragma unroll
                for (int dblk = 0; dblk < 4; ++dblk) {
                    const char* vrow = (const char*)(&Vt[c][dblk * 32 + q31][0]);
                    const bf16x8 vf =
                        *(const bf16x8*)(vrow + ((ks * 32 + h5 * 16) ^ rx));
                    acco[dblk] = __builtin_amdgcn_mfma_f32_32x32x16_bf16(
                        fr.v8, vf, acco[dblk], 0, 0, 0);
                }
            }
        __builtin_amdgcn_s_setprio(0);

        if (t < 31) writeV(c ^ 1);
        __syncthreads();
    }

    float linv = 1.0f / lrun;
#pragma unroll
    for (int r = 0; r < 16; ++r) {
        int qr = (r & 3) + 8 * (r >> 2) + 4 * h5;
        float il = __shfl(linv, qr);
        size_t row = (size_t)(b * 2048 + q0 + wv * 32 + qr) * 2048 + h * 128;
#pragma unroll
        for (int dblk = 0; dblk < 4; ++dblk)
            y[row + dblk * 32 + q31] = (bf16)(acco[dblk][r] * il);
    }
}

// ---------------------------------------------------------------------------
extern "C" void kernel_launch(void* const* d_in, const int* in_sizes, int n_in,
                              void* d_out, int out_size, void* d_ws, size_t ws_size,
                              hipStream_t stream) {
    const float* x = (const float*)d_in[0];
    const float* cs = (const float*)d_in[1];
    const float* sn = (const float*)d_in[2];
    const float* Wq = (const float*)d_in[3];
    const float* Wk = (const float*)d_in[4];
    const float* Wv = (const float*)d_in[5];
    const float* Wo = (const float*)d_in[6];

    char* ws = (char*)d_ws;
    bf16* xb  = (bf16*)(ws + 0);          // 4096x2048
    bf16* wqb = (bf16*)(ws + 16777216);   // [Wq;Wk;Wv;Wo] contiguous
    bf16* wob = (bf16*)(ws + 41943040);
    bf16* qb  = (bf16*)(ws + 50331648);   // q,k,v contiguous planes
    bf16* kb  = (bf16*)(ws + 67108864);
    bf16* vb  = (bf16*)(ws + 83886080);
    bf16* yb  = (bf16*)(ws + 100663296);

    cvtall_kernel<<<dim3(512, 5), 256, 0, stream>>>(x, Wq, Wk, Wv, Wo, xb, wqb);

    // fused QKV: C[4096,6144] = xb @ [Wq;Wk;Wv]^T -> qb/kb/vb planes
    gemm_qkv<<<256, 512, 0, stream>>>(xb, wqb, qb);

    rope_rms<<<dim3(16384, 2), 256, 0, stream>>>(qb, kb, cs, sn);

    attn_kernel<<<dim3(8, 32), 512, 0, stream>>>(qb, kb, vb, yb);

    dim3 g(16, 32);  // N/128, M/128
    gemm_bt<true><<<g, 256, 0, stream>>>(yb, wob, d_out, 4096, 2048, 2048);
}

// Round 18
// 281.475 us; speedup vs baseline: 1.0436x; 1.0436x over previous
//
#include <hip/hip_runtime.h>
#include <hip/hip_bf16.h>
#include <math.h>

typedef __bf16 bf16;
typedef __attribute__((ext_vector_type(8))) __bf16 bf16x8;
typedef __attribute__((ext_vector_type(4))) float f32x4;
typedef __attribute__((ext_vector_type(16))) float f32x16;

#define DEV __device__ __forceinline__

// ---------------------------------------------------------------------------
// async global->LDS, 16B per lane. LDS dest is wave-uniform base + lane*16.
DEV void gload16(const void* g, void* l) {
    __builtin_amdgcn_global_load_lds(
        (__attribute__((address_space(1))) void*)(void*)g,
        (__attribute__((address_space(3))) void*)l, 16, 0, 0);
}

DEV unsigned pk2(float a, float b) {
    union { bf16 h[2]; unsigned u; } z;
    z.h[0] = (bf16)a; z.h[1] = (bf16)b;
    return z.u;
}

// swap a's hi-32-lane contents with b's lo-32-lane contents.
DEV void plswap(unsigned& a, unsigned& b) {
    asm volatile("v_permlane32_swap_b32 %0, %1" : "+v"(a), "+v"(b));
}

DEV f32x16 mfma32(bf16x8 a, bf16x8 b, f32x16 c) {
    return __builtin_amdgcn_mfma_f32_32x32x16_bf16(a, b, c, 0, 0, 0);
}

// ---------------------------------------------------------------------------
// fp32 -> bf16 conversion for x + all 4 weights, one launch, 5 segments.
__global__ __launch_bounds__(256) void cvtall_kernel(const float* __restrict__ x,
                                                     const float* __restrict__ w0,
                                                     const float* __restrict__ w1,
                                                     const float* __restrict__ w2,
                                                     const float* __restrict__ w3,
                                                     bf16* __restrict__ xb,
                                                     bf16* __restrict__ wb) {
    const int seg = blockIdx.y;
    const float* in;
    bf16* o;
    int n8;
    if (seg == 0) { in = x; o = xb; n8 = 1048576; }
    else {
        in = (seg == 1) ? w0 : (seg == 2) ? w1 : (seg == 3) ? w2 : w3;
        o = wb + (size_t)(seg - 1) * 4194304;
        n8 = 524288;
    }
    for (int i = blockIdx.x * 256 + threadIdx.x; i < n8; i += 512 * 256) {
        const float4* p = (const float4*)(in + (size_t)i * 8);
        float4 a = p[0], b = p[1];
        bf16x8 v;
        v[0] = (bf16)a.x; v[1] = (bf16)a.y; v[2] = (bf16)a.z; v[3] = (bf16)a.w;
        v[4] = (bf16)b.x; v[5] = (bf16)b.y; v[6] = (bf16)b.z; v[7] = (bf16)b.w;
        *(bf16x8*)(o + (size_t)i * 8) = v;
    }
}

// ---------------------------------------------------------------------------
// Fused QKV GEMM (r13 proven best, 93 us): 256x384, BK=32, 3-ring (120KB),
// counted vmcnt(5) gate (2-tile load slack — the load-bearing feature; the
// r17 2-deep variant with vmcnt(0) regressed to 119 us), barrier-thinned.
__global__ __launch_bounds__(512, 2) void gemm_qkv(const bf16* __restrict__ A,
                                                   const bf16* __restrict__ Bg,
                                                   bf16* __restrict__ outq) {
    __shared__ __align__(16) bf16 As[3][256 * 32];
    __shared__ __align__(16) bf16 Bs[3][384 * 32];
    const int tid = threadIdx.x, lane = tid & 63, wv = tid >> 6;
    const int q31 = lane & 31, h5 = lane >> 5;
    const int wm = wv >> 2, wn = wv & 3;
    const int K = 2048;

    int lin = blockIdx.x;
    int swz = (lin & 7) * 32 + (lin >> 3);
    const int tm = (swz >> 4) * 256;
    const int tn = (swz & 15) * 384;

    f32x16 acc[4][3] = {};

    auto stageA = [&](int t, int buf) {
#pragma unroll
        for (int l = 0; l < 2; ++l) {
            int chunk = l * 8 + wv;
            int row = chunk * 16 + (lane >> 2);
            int cb = ((lane & 3) * 16) ^ (((row >> 1) & 3) << 4);
            gload16((const char*)(A + (size_t)(tm + row) * K + t * 32) + cb,
                    (char*)(As[buf]) + chunk * 1024);
        }
    };
    auto stageB = [&](int t, int buf) {
#pragma unroll
        for (int l = 0; l < 3; ++l) {
            int chunk = l * 8 + wv;
            int row = chunk * 16 + (lane >> 2);
            int cb = ((lane & 3) * 16) ^ (((row >> 1) & 3) << 4);
            gload16((const char*)(Bg + (size_t)(tn + row) * K + t * 32) + cb,
                    (char*)(Bs[buf]) + chunk * 1024);
        }
    };
    auto rdA = [&](int buf, int mb, int ks) -> bf16x8 {
        int row = wm * 128 + mb * 32 + q31;
        int off = (ks * 32 + h5 * 16) ^ (((row >> 1) & 3) << 4);
        return *(const bf16x8*)((const char*)(As[buf]) + row * 64 + off);
    };
    auto rdB = [&](int buf, int nb, int ks) -> bf16x8 {
        int row = wn * 96 + nb * 32 + q31;
        int off = (ks * 32 + h5 * 16) ^ (((row >> 1) & 3) << 4);
        return *(const bf16x8*)((const char*)(Bs[buf]) + row * 64 + off);
    };

    stageA(0, 0); stageB(0, 0);
    stageA(1, 1); stageB(1, 1);
    asm volatile("s_waitcnt vmcnt(5)" ::: "memory");
    __builtin_amdgcn_s_barrier();

    int cur = 0, nxt2 = 2;
    for (int t = 0; t < 64; ++t) {
        bf16x8 af[2][2], bfr[3][2];
#pragma unroll
        for (int mb = 0; mb < 2; ++mb)
#pragma unroll
            for (int ks = 0; ks < 2; ++ks) af[mb][ks] = rdA(cur, mb, ks);
#pragma unroll
        for (int nb = 0; nb < 3; ++nb)
#pragma unroll
            for (int ks = 0; ks < 2; ++ks) bfr[nb][ks] = rdB(cur, nb, ks);
        if (t < 62) stageA(t + 2, nxt2);
        asm volatile("s_waitcnt lgkmcnt(0)" ::: "memory");
        __builtin_amdgcn_sched_barrier(0);
        __builtin_amdgcn_s_setprio(1);
#pragma unroll
        for (int mb = 0; mb < 2; ++mb)
#pragma unroll
            for (int nb = 0; nb < 3; ++nb)
#pragma unroll
                for (int ks = 0; ks < 2; ++ks)
                    acc[mb][nb] = mfma32(af[mb][ks], bfr[nb][ks], acc[mb][nb]);
        __builtin_amdgcn_s_setprio(0);
#pragma unroll
        for (int mb = 0; mb < 2; ++mb)
#pragma unroll
            for (int ks = 0; ks < 2; ++ks) af[mb][ks] = rdA(cur, 2 + mb, ks);
        if (t < 62) stageB(t + 2, nxt2);
        asm volatile("s_waitcnt lgkmcnt(0)" ::: "memory");
        __builtin_amdgcn_sched_barrier(0);
        __builtin_amdgcn_s_setprio(1);
#pragma unroll
        for (int mb = 0; mb < 2; ++mb)
#pragma unroll
            for (int nb = 0; nb < 3; ++nb)
#pragma unroll
                for (int ks = 0; ks < 2; ++ks)
                    acc[2 + mb][nb] = mfma32(af[mb][ks], bfr[nb][ks], acc[2 + mb][nb]);
        __builtin_amdgcn_s_setprio(0);
        if (t < 62)
            asm volatile("s_waitcnt vmcnt(5)" ::: "memory");
        else
            asm volatile("s_waitcnt vmcnt(0)" ::: "memory");
        __builtin_amdgcn_s_barrier();
        cur = (cur == 2) ? 0 : cur + 1;
        nxt2 = (nxt2 == 2) ? 0 : nxt2 + 1;
    }

#pragma unroll
    for (int mb = 0; mb < 4; ++mb)
#pragma unroll
        for (int nb = 0; nb < 3; ++nb) {
            int colbase = tn + wn * 96 + nb * 32;
            bf16* op = outq + (size_t)(colbase >> 11) * 8388608 +
                       (colbase & 2047) + q31;
#pragma unroll
            for (int r = 0; r < 16; ++r) {
                int row = tm + wm * 128 + mb * 32 + (r & 3) + 8 * (r >> 2) + 4 * h5;
                op[(size_t)row * 2048] = (bf16)acc[mb][nb][r];
            }
        }
}

// ---------------------------------------------------------------------------
// C[M,N] = A[M,K] @ B[N,K]^T. 128x128 tile, BK=64, 4 waves. Wo GEMM.
template <bool F32OUT>
__global__ __launch_bounds__(256) void gemm_bt(const bf16* __restrict__ A,
                                               const bf16* __restrict__ B,
                                               void* __restrict__ Cout,
                                               int M, int N, int K) {
    __shared__ __align__(16) bf16 As[128 * 64];
    __shared__ __align__(16) bf16 Bs[128 * 64];
    const int tid = threadIdx.x, lane = tid & 63, wv = tid >> 6;
    int lin = blockIdx.y * 16 + blockIdx.x;
    int swz = (lin & 7) * 64 + (lin >> 3);
    const int tm = (swz >> 4) * 128, tn = (swz & 15) * 128;
    const int wr = (wv >> 1) * 64, wc = (wv & 1) * 64;

    f32x4 acc[4][4] = {};
    const int scb = (lane & 7) * 16;

    for (int k0 = 0; k0 < K; k0 += 64) {
#pragma unroll
        for (int i = 0; i < 4; ++i) {
            int chunk = wv * 4 + i;
            int row = chunk * 8 + (lane >> 3);
            int cb = scb ^ ((row & 7) << 4);
            gload16((const char*)(A + (size_t)(tm + row) * K + k0) + cb,
                    (char*)As + chunk * 1024);
            gload16((const char*)(B + (size_t)(tn + row) * K + k0) + cb,
                    (char*)Bs + chunk * 1024);
        }
        __syncthreads();
#pragma unroll
        for (int kk = 0; kk < 2; ++kk) {
            bf16x8 af[4], bfr[4];
#pragma unroll
            for (int m = 0; m < 4; ++m) {
                int row = wr + m * 16 + (lane & 15);
                int cb = (kk * 64 + ((lane >> 4) * 16)) ^ ((row & 7) << 4);
                af[m] = *(const bf16x8*)((const char*)As + row * 128 + cb);
            }
#pragma unroll
            for (int n = 0; n < 4; ++n) {
                int row = wc + n * 16 + (lane & 15);
                int cb = (kk * 64 + ((lane >> 4) * 16)) ^ ((row & 7) << 4);
                bfr[n] = *(const bf16x8*)((const char*)Bs + row * 128 + cb);
            }
#pragma unroll
            for (int m = 0; m < 4; ++m)
#pragma unroll
                for (int n = 0; n < 4; ++n)
                    acc[m][n] = __builtin_amdgcn_mfma_f32_16x16x32_bf16(
                        af[m], bfr[n], acc[m][n], 0, 0, 0);
        }
        __syncthreads();
    }
#pragma unroll
    for (int m = 0; m < 4; ++m)
#pragma unroll
        for (int n = 0; n < 4; ++n)
#pragma unroll
            for (int r = 0; r < 4; ++r) {
                int row = tm + wr + m * 16 + (lane >> 4) * 4 + r;
                int col = tn + wc + n * 16 + (lane & 15);
                if (F32OUT)
                    ((float*)Cout)[(size_t)row * N + col] = acc[m][n][r];
                else
                    ((bf16*)Cout)[(size_t)row * N + col] = (bf16)acc[m][n][r];
            }
}

// ---------------------------------------------------------------------------
// RoPE + RMSNorm(*1.2), in-place. q pre-scaled by (1/sqrt(128))*log2(e).
__global__ __launch_bounds__(256) void rope_rms(bf16* __restrict__ q,
                                                bf16* __restrict__ k,
                                                const float* __restrict__ cosp,
                                                const float* __restrict__ sinp) {
    int gw = blockIdx.x * 4 + (threadIdx.x >> 6);
    int lane = threadIdx.x & 63;
    bf16* base = (blockIdx.y == 0) ? q : k;
    int m = gw >> 4, h = gw & 15;
    int s = m & 2047;
    bf16* p = base + (size_t)m * 2048 + h * 128;
    float x1 = (float)p[lane], x2 = (float)p[lane + 64];
    float c = cosp[s * 64 + lane], si = sinp[s * 64 + lane];
    float r1 = x1 * c + x2 * si;
    float r2 = x2 * c - x1 * si;
    float ss = r1 * r1 + r2 * r2;
#pragma unroll
    for (int msk = 1; msk < 64; msk <<= 1) ss += __shfl_xor(ss, msk);
    float sc = rsqrtf(ss * (1.0f / 128.0f) + 1.1920928955078125e-07f) * 1.2f;
    if (blockIdx.y == 0) sc *= (0.08838834764831845f * 1.4426950408889634f);
    p[lane] = (bf16)(r1 * sc);
    p[lane + 64] = (bf16)(r2 * sc);
}

// ---------------------------------------------------------------------------
// Flash attention fwd (r15 exact, 116.2 us): 32x32x16 MFMA, swapped QK^T,
// P in registers via permlane32_swap. 8 waves x 32 q = 256 q/block.
__global__ __launch_bounds__(512, 2) void attn_kernel(const bf16* __restrict__ q,
                                                      const bf16* __restrict__ k,
                                                      const bf16* __restrict__ v,
                                                      bf16* __restrict__ y) {
    __shared__ __align__(16) bf16 Ks[2][64 * 128];
    __shared__ __align__(16) bf16 Vt[2][128][72];

    const int tid = threadIdx.x, lane = tid & 63, wv = tid >> 6;
    const int q31 = lane & 31, h5 = lane >> 5;

    int wgid = blockIdx.y * 8 + blockIdx.x;
    int xcd = wgid & 7, j = wgid >> 3;
    const int bh = xcd * 4 + (j >> 3);
    const int qblk = j & 7;
    const int b = bh >> 4, h = bh & 15;
    const int q0 = qblk * 256;

    const bf16* qptr = q + (size_t)(b * 2048 + q0 + wv * 32 + q31) * 2048 +
                       h * 128 + h5 * 8;
    bf16x8 qf[8];
#pragma unroll
    for (int ks = 0; ks < 8; ++ks) qf[ks] = *(const bf16x8*)(qptr + ks * 16);

    float mrun = -INFINITY, lrun = 0.f;
    f32x16 acco[4] = {};

    const int p = tid & 63, rg = tid >> 6;
    const bf16* vbase = v + (size_t)(b * 2048 + rg * 8) * 2048 + h * 128 + 2 * p;
    const bf16* kbase = k + (size_t)(b * 2048) * 2048 + h * 128;
    const int vx = (((p >> 2) & 1) << 4) ^ (((p >> 3) & 1) << 5);

    unsigned u[8];

    auto stageK = [&](int t, int buf) {
#pragma unroll
        for (int i = 0; i < 2; ++i) {
            int chunk = wv * 2 + i;
            int row = chunk * 4 + (lane >> 4);
            int cb = ((lane & 15) * 16) ^ ((row & 7) << 4);
            gload16((const char*)(kbase + (size_t)(t * 64 + row) * 2048) + cb,
                    (char*)(Ks[buf]) + chunk * 1024);
        }
    };
    auto loadV = [&](int t) {
        const bf16* vp = vbase + (size_t)(t * 64) * 2048;
#pragma unroll
        for (int jj = 0; jj < 8; ++jj)
            u[jj] = *(const unsigned*)(vp + (size_t)jj * 2048);
    };
    auto writeV = [&](int buf) {
        union { unsigned short s[8]; bf16x8 v8; } lo, hi;
#pragma unroll
        for (int jj = 0; jj < 8; ++jj) {
            lo.s[jj] = (unsigned short)(u[jj] & 0xffff);
            hi.s[jj] = (unsigned short)(u[jj] >> 16);
        }
        char* r0 = (char*)(&Vt[buf][2 * p][0]);
        char* r1 = (char*)(&Vt[buf][2 * p + 1][0]);
        *(bf16x8*)(r0 + ((rg * 16) ^ vx)) = lo.v8;
        *(bf16x8*)(r1 + ((rg * 16) ^ vx)) = hi.v8;
    };

    stageK(0, 0);
    loadV(0);
    writeV(0);
    __syncthreads();

    const int rx = (((q31 >> 3) & 1) << 4) ^ (((q31 >> 4) & 1) << 5);

    for (int t = 0; t < 32; ++t) {
        const int c = t & 1;
        if (t < 31) {
            stageK(t + 1, c ^ 1);
            loadV(t + 1);
        }

        f32x16 st[2];
        __builtin_amdgcn_s_setprio(1);
#pragma unroll
        for (int kvb = 0; kvb < 2; ++kvb) {
            f32x16 a = {};
#pragma unroll
            for (int ks = 0; ks < 8; ++ks) {
                int row = kvb * 32 + q31;
                int cb = (32 * ks + 16 * h5) ^ ((row & 7) << 4);
                const bf16x8 kf =
                    *(const bf16x8*)((const char*)(Ks[c]) + row * 256 + cb);
                a = __builtin_amdgcn_mfma_f32_32x32x16_bf16(kf, qf[ks], a, 0, 0, 0);
            }
            st[kvb] = a;
        }
        __builtin_amdgcn_s_setprio(0);

        float t8[8];
#pragma unroll
        for (int r = 0; r < 8; ++r)
            t8[r] = fmaxf(fmaxf(st[0][r], st[0][r + 8]),
                          fmaxf(st[1][r], st[1][r + 8]));
        float mx = fmaxf(fmaxf(fmaxf(t8[0], t8[1]), fmaxf(t8[2], t8[3])),
                         fmaxf(fmaxf(t8[4], t8[5]), fmaxf(t8[6], t8[7])));
        mx = fmaxf(mx, __shfl_xor(mx, 32));

        if (__any(mx - mrun > 8.0f)) {
            float mn = fmaxf(mrun, mx);
            float alpha = exp2f(mrun - mn);
            mrun = mn;
            lrun *= alpha;
#pragma unroll
            for (int r = 0; r < 16; ++r) {
                int qr = (r & 3) + 8 * (r >> 2) + 4 * h5;
                float al = __shfl(alpha, qr);
                acco[0][r] *= al; acco[1][r] *= al;
                acco[2][r] *= al; acco[3][r] *= al;
            }
        }

        unsigned w[2][8];
        float rsa = 0.f, rsb = 0.f;
#pragma unroll
        for (int kvb = 0; kvb < 2; ++kvb)
#pragma unroll
            for (int i = 0; i < 8; ++i) {
                float p0 = exp2f(st[kvb][2 * i] - mrun);
                float p1 = exp2f(st[kvb][2 * i + 1] - mrun);
                if (i & 1) rsb += p0 + p1; else rsa += p0 + p1;
                w[kvb][i] = pk2(p0, p1);
            }
        float rs = rsa + rsb;
        rs += __shfl_xor(rs, 32);
        lrun += rs;

        __builtin_amdgcn_s_setprio(1);
#pragma unroll
        for (int b2 = 0; b2 < 2; ++b2)
#pragma unroll
            for (int ksl = 0; ksl < 2; ++ksl) {
                const int ks = b2 * 2 + ksl, u0 = ksl * 4;
                unsigned f0 = w[b2][u0 + 0], f2 = w[b2][u0 + 2];
                unsigned f1 = w[b2][u0 + 1], f3 = w[b2][u0 + 3];
                plswap(f0, f2);
                plswap(f1, f3);
                union { unsigned uu[4]; bf16x8 v8; } fr;
                fr.uu[0] = f0; fr.uu[1] = f1; fr.uu[2] = f2; fr.uu[3] = f3;
#pragma unroll
                for (int dblk = 0; dblk < 4; ++dblk) {
                    const char* vrow = (const char*)(&Vt[c][dblk * 32 + q31][0]);
                    const bf16x8 vf =
                        *(const bf16x8*)(vrow + ((ks * 32 + h5 * 16) ^ rx));
                    acco[dblk] = __builtin_amdgcn_mfma_f32_32x32x16_bf16(
                        fr.v8, vf, acco[dblk], 0, 0, 0);
                }
            }
        __builtin_amdgcn_s_setprio(0);

        if (t < 31) writeV(c ^ 1);
        __syncthreads();
    }

    float linv = 1.0f / lrun;
#pragma unroll
    for (int r = 0; r < 16; ++r) {
        int qr = (r & 3) + 8 * (r >> 2) + 4 * h5;
        float il = __shfl(linv, qr);
        size_t row = (size_t)(b * 2048 + q0 + wv * 32 + qr) * 2048 + h * 128;
#pragma unroll
        for (int dblk = 0; dblk < 4; ++dblk)
            y[row + dblk * 32 + q31] = (bf16)(acco[dblk][r] * il);
    }
}

// ---------------------------------------------------------------------------
extern "C" void kernel_launch(void* const* d_in, const int* in_sizes, int n_in,
                              void* d_out, int out_size, void* d_ws, size_t ws_size,
                              hipStream_t stream) {
    const float* x = (const float*)d_in[0];
    const float* cs = (const float*)d_in[1];
    const float* sn = (const float*)d_in[2];
    const float* Wq = (const float*)d_in[3];
    const float* Wk = (const float*)d_in[4];
    const float* Wv = (const float*)d_in[5];
    const float* Wo = (const float*)d_in[6];

    char* ws = (char*)d_ws;
    bf16* xb  = (bf16*)(ws + 0);          // 4096x2048
    bf16* wqb = (bf16*)(ws + 16777216);   // [Wq;Wk;Wv;Wo] contiguous
    bf16* wob = (bf16*)(ws + 41943040);
    bf16* qb  = (bf16*)(ws + 50331648);   // q,k,v contiguous planes
    bf16* kb  = (bf16*)(ws + 67108864);
    bf16* vb  = (bf16*)(ws + 83886080);
    bf16* yb  = (bf16*)(ws + 100663296);

    cvtall_kernel<<<dim3(512, 5), 256, 0, stream>>>(x, Wq, Wk, Wv, Wo, xb, wqb);

    // fused QKV: C[4096,6144] = xb @ [Wq;Wk;Wv]^T -> qb/kb/vb planes
    gemm_qkv<<<256, 512, 0, stream>>>(xb, wqb, qb);

    rope_rms<<<dim3(16384, 2), 256, 0, stream>>>(qb, kb, cs, sn);

    attn_kernel<<<dim3(8, 32), 512, 0, stream>>>(qb, kb, vb, yb);

    dim3 g(16, 32);  // N/128, M/128
    gemm_bt<true><<<g, 256, 0, stream>>>(yb, wob, d_out, 4096, 2048, 2048);
}